// Round 1
// baseline (126.183 us; speedup 1.0000x reference)
//
#include <hip/hip_runtime.h>
#include <hip/hip_bf16.h>

// RandomProjectionQuantizer:
//  x:(16,2048,320) f32, mask:(16,2048) i32 (exactly 16384 ones),
//  W:(16,320) f32, codebook:(8192,16) f32  ->  scalar int32 label
//  label = argmin over flattened (16384 x 8192) distance matrix, rows in
//  ascending masked-index order (jnp.nonzero order), first-index tie-break.

#define NROWS_TOTAL 32768   // B*L
#define NMASK       16384
#define D           320
#define CDIM        16
#define NCODES      8192

// ---------------- Kernel 1: chunk scan (order-preserving compaction ranks) ---
// chunk = 64 consecutive rows (one wave). chunkpref[c] = #masked rows before chunk c.
__global__ __launch_bounds__(1024) void prep_kernel(const int* __restrict__ mask,
                                                    int* __restrict__ chunkpref,
                                                    unsigned long long* __restrict__ key) {
  __shared__ int a[512], b[512];
  int tid  = threadIdx.x;
  int wave = tid >> 6, lane = tid & 63;
  for (int j = 0; j < 32; ++j) {
    int c = wave * 32 + j;                       // 16 waves * 32 = 512 chunks
    int m = mask[c * 64 + lane];
    unsigned long long bal = __ballot(m != 0);
    if (lane == 0) a[c] = __popcll(bal);
  }
  __syncthreads();
  // Hillis-Steele inclusive scan over 512 chunk sums (double-buffered)
  int* src = a; int* dst = b;
  for (int off = 1; off < 512; off <<= 1) {
    if (tid < 512) dst[tid] = src[tid] + (tid >= off ? src[tid - off] : 0);
    __syncthreads();
    int* t = src; src = dst; dst = t;
  }
  if (tid < 512) chunkpref[tid] = (tid == 0) ? 0 : src[tid - 1];
  if (tid == 0) *key = 0xFFFFFFFFFFFFFFFFull;    // init global argmin key
}

// ---------------- Kernel 2: codebook row norms ------------------------------
__global__ __launch_bounds__(256) void c2_kernel(const float* __restrict__ cb,
                                                 float* __restrict__ c2) {
  int k = blockIdx.x * 256 + threadIdx.x;        // 8192 threads
  const float4* p = (const float4*)(cb + (long)k * CDIM);
  float s = 0.f;
#pragma unroll
  for (int q = 0; q < 4; ++q) {
    float4 v = p[q];
    s = fmaf(v.x, v.x, s); s = fmaf(v.y, v.y, s);
    s = fmaf(v.z, v.z, s); s = fmaf(v.w, v.w, s);
  }
  c2[k] = s;
}

// ---------------- Kernel 3: gather + project masked rows --------------------
// lane-per-row; W staged in LDS, read as wave-uniform broadcasts.
// writes tgtm[rank][c] = -2 * t_c  and t2arr[rank] = ||t||^2.
__global__ __launch_bounds__(128) void project_kernel(const float* __restrict__ x,
                                                      const int* __restrict__ mask,
                                                      const int* __restrict__ chunkpref,
                                                      const float* __restrict__ W,
                                                      float* __restrict__ tgtm,
                                                      float* __restrict__ t2arr) {
  __shared__ float Wl[CDIM * D];                 // 20 KiB
  int tid = threadIdx.x;
  for (int i = tid; i < (CDIM * D) / 4; i += 128)
    ((float4*)Wl)[i] = ((const float4*)W)[i];
  __syncthreads();

  int wave = blockIdx.x * 2 + (tid >> 6);        // 256 blocks * 2 waves = 512
  int lane = tid & 63;
  int row  = wave * 64 + lane;
  int m = mask[row];
  unsigned long long bal = __ballot(m != 0);
  int rank = chunkpref[wave] + __popcll(bal & ((1ull << lane) - 1ull));
  if (!m) return;

  const float4* xr = (const float4*)(x + (long)row * D);
  float pd[CDIM];
#pragma unroll
  for (int c = 0; c < CDIM; ++c) pd[c] = 0.f;
#pragma unroll 2
  for (int j = 0; j < D / 4; ++j) {              // 80 float4 per row
    float4 xv = xr[j];
#pragma unroll
    for (int c = 0; c < CDIM; ++c) {             // W read is wave-uniform -> broadcast
      const float4 wv = *(const float4*)&Wl[c * D + j * 4];
      float acc = fmaf(xv.x, wv.x, pd[c]);
      acc = fmaf(xv.y, wv.y, acc);
      acc = fmaf(xv.z, wv.z, acc);
      pd[c] = fmaf(xv.w, wv.w, acc);
    }
  }
  float t2 = 0.f;
#pragma unroll
  for (int c = 0; c < CDIM; ++c) t2 = fmaf(pd[c], pd[c], t2);
  float* op = tgtm + (long)rank * CDIM;
#pragma unroll
  for (int c = 0; c < CDIM; ++c) op[c] = -2.0f * pd[c];
  t2arr[rank] = t2;
}

// ---------------- Kernel 4: distances + global argmin -----------------------
// Each thread holds 8 rows' (-2t) in registers; streams a 128-code LDS tile.
// val = c2[k] + sum((-2t) * c)   (t2 added once per row at the end).
__global__ __launch_bounds__(256, 2) void argmin_kernel(const float* __restrict__ tgtm,
                                                        const float* __restrict__ t2arr,
                                                        const float* __restrict__ cb,
                                                        const float* __restrict__ c2,
                                                        unsigned long long* __restrict__ key) {
  __shared__ float cbl[128 * CDIM];              // 8 KiB code tile
  __shared__ float c2l[128];
  __shared__ unsigned long long red[256];
  int tid    = threadIdx.x;
  int rowblk = (int)blockIdx.x >> 6;             // 8 row blocks of 2048 rows
  int seg    = (int)blockIdx.x & 63;             // 64 code segments of 128
  int k0     = seg * 128;

  for (int i = tid; i < (128 * CDIM) / 4; i += 256)
    ((float4*)cbl)[i] = ((const float4*)(cb + (long)k0 * CDIM))[i];
  if (tid < 128) c2l[tid] = c2[k0 + tid];
  __syncthreads();

  float tm[8][CDIM];
  float t2r[8];
#pragma unroll
  for (int rr = 0; rr < 8; ++rr) {
    int r = rowblk * 2048 + tid + rr * 256;
    const float4* tp = (const float4*)(tgtm + (long)r * CDIM);
#pragma unroll
    for (int q = 0; q < 4; ++q) {
      float4 v = tp[q];
      tm[rr][q * 4 + 0] = v.x; tm[rr][q * 4 + 1] = v.y;
      tm[rr][q * 4 + 2] = v.z; tm[rr][q * 4 + 3] = v.w;
    }
    t2r[rr] = t2arr[r];
  }

  float minv[8]; int mink[8];
#pragma unroll
  for (int rr = 0; rr < 8; ++rr) { minv[rr] = 3.4e38f; mink[rr] = 0; }

  for (int kk = 0; kk < 128; ++kk) {
    float c2k = c2l[kk];                          // uniform broadcasts
    const float4* cp = (const float4*)&cbl[kk * CDIM];
    float4 c0 = cp[0], c1 = cp[1], c2v = cp[2], c3 = cp[3];
#pragma unroll
    for (int rr = 0; rr < 8; ++rr) {              // 8 independent FMA chains
      float acc = fmaf(tm[rr][0],  c0.x, c2k);
      acc = fmaf(tm[rr][1],  c0.y, acc);
      acc = fmaf(tm[rr][2],  c0.z, acc);
      acc = fmaf(tm[rr][3],  c0.w, acc);
      acc = fmaf(tm[rr][4],  c1.x, acc);
      acc = fmaf(tm[rr][5],  c1.y, acc);
      acc = fmaf(tm[rr][6],  c1.z, acc);
      acc = fmaf(tm[rr][7],  c1.w, acc);
      acc = fmaf(tm[rr][8],  c2v.x, acc);
      acc = fmaf(tm[rr][9],  c2v.y, acc);
      acc = fmaf(tm[rr][10], c2v.z, acc);
      acc = fmaf(tm[rr][11], c2v.w, acc);
      acc = fmaf(tm[rr][12], c3.x, acc);
      acc = fmaf(tm[rr][13], c3.y, acc);
      acc = fmaf(tm[rr][14], c3.z, acc);
      acc = fmaf(tm[rr][15], c3.w, acc);
      if (acc < minv[rr]) { minv[rr] = acc; mink[rr] = kk; }
    }
  }

  // pack (monotone float bits << 32) | flat_index; min => first-index tie-break
  unsigned long long best = 0xFFFFFFFFFFFFFFFFull;
  int rbase = rowblk * 2048 + tid;
#pragma unroll
  for (int rr = 0; rr < 8; ++rr) {
    float tot = t2r[rr] + minv[rr];
    unsigned int u = __float_as_uint(tot);
    u = (u & 0x80000000u) ? ~u : (u | 0x80000000u);
    unsigned int flat = (unsigned int)(rbase + rr * 256) * (unsigned int)NCODES
                      + (unsigned int)(k0 + mink[rr]);
    unsigned long long kk2 = ((unsigned long long)u << 32) | (unsigned long long)flat;
    best = (kk2 < best) ? kk2 : best;
  }
  red[tid] = best;
  __syncthreads();
  for (int s = 128; s > 0; s >>= 1) {
    if (tid < s) { if (red[tid + s] < red[tid]) red[tid] = red[tid + s]; }
    __syncthreads();
  }
  if (tid == 0) atomicMin(key, red[0]);
}

// ---------------- Kernel 5: emit label ---------------------------------------
__global__ void finish_kernel(const unsigned long long* __restrict__ key,
                              int* __restrict__ out) {
  out[0] = (int)(unsigned int)(*key & 0xFFFFFFFFull);
}

extern "C" void kernel_launch(void* const* d_in, const int* in_sizes, int n_in,
                              void* d_out, int out_size, void* d_ws, size_t ws_size,
                              hipStream_t stream) {
  const float* x    = (const float*)d_in[0];   // (16,2048,320)
  const int*   mask = (const int*)d_in[1];     // (16,2048)
  const float* W    = (const float*)d_in[2];   // (16,320)
  const float* cb   = (const float*)d_in[3];   // (8192,16)
  int* out = (int*)d_out;

  char* ws = (char*)d_ws;
  int*   chunkpref          = (int*)ws;                              // 2 KiB
  unsigned long long* key   = (unsigned long long*)(ws + 2048);      // 8 B
  float* t2arr              = (float*)(ws + 4096);                   // 64 KiB
  float* c2                 = (float*)(ws + 4096 + 65536);           // 32 KiB
  float* tgtm               = (float*)(ws + 4096 + 65536 + 32768);   // 1 MiB

  prep_kernel<<<1, 1024, 0, stream>>>(mask, chunkpref, key);
  c2_kernel<<<NCODES / 256, 256, 0, stream>>>(cb, c2);
  project_kernel<<<256, 128, 0, stream>>>(x, mask, chunkpref, W, tgtm, t2arr);
  argmin_kernel<<<512, 256, 0, stream>>>(tgtm, t2arr, cb, c2, key);
  finish_kernel<<<1, 1, 0, stream>>>(key, out);
}